// Round 3
// baseline (238.629 us; speedup 1.0000x reference)
//
#include <hip/hip_runtime.h>
#include <math.h>

#define B 8
#define S 1024
#define D 1024
#define F 3584

#define KSV 32   // split-K for 1024x1024 matvecs (chunk 32)
#define KSG 16   // split-K for gate/up (chunk 64)
#define KSD 56   // split-K for down (chunk 64)

// ---------------- block-wide sum for 256-thread blocks ----------------
__device__ __forceinline__ float block_sum256(float v, volatile float* buf) {
  #pragma unroll
  for (int o = 32; o; o >>= 1) v += __shfl_down(v, o);   // wave64 reduce
  __syncthreads();
  if ((threadIdx.x & 63) == 0) buf[threadIdx.x >> 6] = v;
  __syncthreads();
  return buf[0] + buf[1] + buf[2] + buf[3];
}

// K1: h1[b] = rmsnorm(hidden[b,0,:], ln1_w).  grid=B, block=256 (float4/thread).
__global__ void k_rms1(const float* __restrict__ hs, const float* __restrict__ w,
                       float* __restrict__ h1) {
  __shared__ float buf[4];
  int b = blockIdx.x;
  int idx = threadIdx.x * 4;
  float4 x = *(const float4*)(hs + (size_t)b * S * D + idx);
  float ss = x.x * x.x + x.y * x.y + x.z * x.z + x.w * x.w;
  float tot = block_sum256(ss, buf);
  float sc = rsqrtf(tot * (1.f / (float)D) + 1e-6f);
  float4 wv = *(const float4*)(w + idx);
  float4 o;
  o.x = x.x * sc * wv.x; o.y = x.y * sc * wv.y;
  o.z = x.z * sc * wv.z; o.w = x.w * sc * wv.w;
  *(float4*)(h1 + b * D + idx) = o;
}

// Split-K matvec partials: P[p][bb][j] = sum_{i in chunk p} X[bb][i]*W[i][j].
// grid=(4, KSV), block=64, 4 cols/thread, batch-4 K-steps (8 loads in flight).
__global__ void k_mvp(const float* __restrict__ X, const float* __restrict__ W,
                      float* __restrict__ P) {
  const int chunk = D / KSV;  // 32
  int j = (blockIdx.x * 64 + threadIdx.x) * 4;
  int i0 = blockIdx.y * chunk;
  const float4* Wp = (const float4*)(W + (size_t)i0 * D + j);
  float4 acc[8];
  #pragma unroll
  for (int bb = 0; bb < 8; bb++) acc[bb] = make_float4(0.f, 0.f, 0.f, 0.f);
  for (int ii = 0; ii < chunk; ii += 4) {
    float4 wb[4];
    #pragma unroll
    for (int u = 0; u < 4; u++) wb[u] = Wp[(size_t)u * (D / 4)];
    float4 xb[8];
    #pragma unroll
    for (int bb = 0; bb < 8; bb++)
      xb[bb] = *(const float4*)(X + bb * D + i0 + ii);   // wave-uniform
    #pragma unroll
    for (int u = 0; u < 4; u++) {
      #pragma unroll
      for (int bb = 0; bb < 8; bb++) {
        float xv = ((const float*)&xb[bb])[u];
        acc[bb].x += xv * wb[u].x; acc[bb].y += xv * wb[u].y;
        acc[bb].z += xv * wb[u].z; acc[bb].w += xv * wb[u].w;
      }
    }
    Wp += (size_t)(D / 4) * 4;
  }
  #pragma unroll
  for (int bb = 0; bb < 8; bb++)
    *(float4*)(P + ((size_t)blockIdx.y * 8 + bb) * D + j) = acc[bb];
}

// Reduce KSV partials -> v0[8][1024]. grid=8, block=256 (float4/thread).
__global__ void k_red8k(const float* __restrict__ P, float* __restrict__ v0) {
  int o = (blockIdx.x * 256 + threadIdx.x);   // float4 index in [0,2048)
  const float4* P4 = (const float4*)P;
  float4 s = make_float4(0.f, 0.f, 0.f, 0.f);
  #pragma unroll 8
  for (int p = 0; p < KSV; p++) {
    float4 v = P4[(size_t)p * (8 * D / 4) + o];
    s.x += v.x; s.y += v.y; s.z += v.z; s.w += v.w;
  }
  ((float4*)v0)[o] = s;
}

// K4: xr = hidden[b,0] + sum_p Op; h2 = rmsnorm(xr, ln2); router top-1.
// grid=B, block=256 (float4/thread).
__global__ void k_mid(const float* __restrict__ hs, const float* __restrict__ Op,
                      const float* __restrict__ ln2, const float* __restrict__ rw,
                      float* __restrict__ xr, float* __restrict__ h2,
                      float* __restrict__ topw, int* __restrict__ sel) {
  __shared__ float buf[4];
  int b = blockIdx.x;
  int idx = threadIdx.x * 4;
  float4 x = *(const float4*)(hs + (size_t)b * S * D + idx);
  #pragma unroll 8
  for (int p = 0; p < KSV; p++) {
    float4 v = *(const float4*)(Op + ((size_t)p * 8 + b) * D + idx);
    x.x += v.x; x.y += v.y; x.z += v.z; x.w += v.w;
  }
  *(float4*)(xr + b * D + idx) = x;
  float ss = x.x * x.x + x.y * x.y + x.z * x.z + x.w * x.w;
  float tot = block_sum256(ss, buf);
  float sc = rsqrtf(tot * (1.f / (float)D) + 1e-6f);
  float4 wv = *(const float4*)(ln2 + idx);
  float4 h;
  h.x = x.x * sc * wv.x; h.y = x.y * sc * wv.y;
  h.z = x.z * sc * wv.z; h.w = x.w * sc * wv.w;
  *(float4*)(h2 + b * D + idx) = h;
  float r0 = 0.f, r1 = 0.f;
  const float* hv = (const float*)&h;
  #pragma unroll
  for (int r = 0; r < 4; r++) {
    r0 += hv[r] * rw[(idx + r) * 2 + 0];
    r1 += hv[r] * rw[(idx + r) * 2 + 1];
  }
  r0 = block_sum256(r0, buf);
  r1 = block_sum256(r1, buf);
  if (threadIdx.x == 0) {
    float m = fmaxf(r0, r1);
    float e0 = __expf(r0 - m), e1 = __expf(r1 - m);
    float inv = 1.f / (e0 + e1);
    float p0 = e0 * inv, p1 = e1 * inv;
    topw[b] = fmaxf(p0, p1);
    sel[b] = (p1 > p0) ? 1 : 0;
  }
}

// K5: split-K partials of h2@gate_w[e] and h2@up_w[e], both experts.
// grid=(F/256, KSG, 2), block=64, 4 cols/thread, batch-4 (8 loads in flight).
__global__ void k_gateup(const float* __restrict__ h2, const float* __restrict__ gw,
                         const float* __restrict__ uw, float* __restrict__ Gp,
                         float* __restrict__ Up) {
  const int chunk = D / KSG;  // 64
  int e = blockIdx.z;
  int j = (blockIdx.x * 64 + threadIdx.x) * 4;
  int i0 = blockIdx.y * chunk;
  const float4* G = (const float4*)(gw + (size_t)e * D * F + (size_t)i0 * F + j);
  const float4* U = (const float4*)(uw + (size_t)e * D * F + (size_t)i0 * F + j);
  float4 ag[8], au[8];
  #pragma unroll
  for (int bb = 0; bb < 8; bb++) {
    ag[bb] = make_float4(0.f, 0.f, 0.f, 0.f);
    au[bb] = make_float4(0.f, 0.f, 0.f, 0.f);
  }
  for (int ii = 0; ii < chunk; ii += 4) {
    float4 wg[4], wu[4];
    #pragma unroll
    for (int u = 0; u < 4; u++) {
      wg[u] = G[(size_t)u * (F / 4)];
      wu[u] = U[(size_t)u * (F / 4)];
    }
    float4 xb[8];
    #pragma unroll
    for (int bb = 0; bb < 8; bb++)
      xb[bb] = *(const float4*)(h2 + bb * D + i0 + ii);   // wave-uniform
    #pragma unroll
    for (int u = 0; u < 4; u++) {
      #pragma unroll
      for (int bb = 0; bb < 8; bb++) {
        float xv = ((const float*)&xb[bb])[u];
        ag[bb].x += xv * wg[u].x; ag[bb].y += xv * wg[u].y;
        ag[bb].z += xv * wg[u].z; ag[bb].w += xv * wg[u].w;
        au[bb].x += xv * wu[u].x; au[bb].y += xv * wu[u].y;
        au[bb].z += xv * wu[u].z; au[bb].w += xv * wu[u].w;
      }
    }
    G += (size_t)(F / 4) * 4;
    U += (size_t)(F / 4) * 4;
  }
  #pragma unroll
  for (int bb = 0; bb < 8; bb++) {
    size_t o = (((size_t)blockIdx.y * 2 + e) * 8 + bb) * F + j;
    *(float4*)(Gp + o) = ag[bb];
    *(float4*)(Up + o) = au[bb];
  }
}

// K6: g = silu(sum_p Gp) * (sum_p Up). grid=56, block=256 (float4/thread).
__global__ void k_silu_red(const float* __restrict__ Gp, const float* __restrict__ Up,
                           float* __restrict__ g) {
  int o = blockIdx.x * 256 + threadIdx.x;   // float4 index in [0, 14336)
  const float4* G4 = (const float4*)Gp;
  const float4* U4 = (const float4*)Up;
  float4 ga = make_float4(0.f, 0.f, 0.f, 0.f);
  float4 ua = make_float4(0.f, 0.f, 0.f, 0.f);
  #pragma unroll 8
  for (int p = 0; p < KSG; p++) {
    float4 gv = G4[(size_t)p * (2 * 8 * F / 4) + o];
    float4 uv = U4[(size_t)p * (2 * 8 * F / 4) + o];
    ga.x += gv.x; ga.y += gv.y; ga.z += gv.z; ga.w += gv.w;
    ua.x += uv.x; ua.y += uv.y; ua.z += uv.z; ua.w += uv.w;
  }
  float4 r;
  r.x = (ga.x / (1.f + __expf(-ga.x))) * ua.x;
  r.y = (ga.y / (1.f + __expf(-ga.y))) * ua.y;
  r.z = (ga.z / (1.f + __expf(-ga.z))) * ua.z;
  r.w = (ga.w / (1.f + __expf(-ga.w))) * ua.w;
  ((float4*)g)[o] = r;
}

// K7: split-K partials of g[e][b]@down_w[e].
// grid=(4, KSD, 2), block=64, 4 cols/thread, batch-4.
__global__ void k_down(const float* __restrict__ g, const float* __restrict__ dw,
                       float* __restrict__ Dp) {
  const int chunk = F / KSD;  // 64
  int e = blockIdx.z;
  int j = (blockIdx.x * 64 + threadIdx.x) * 4;
  int i0 = blockIdx.y * chunk;
  const float4* W = (const float4*)(dw + (size_t)e * F * D + (size_t)i0 * D + j);
  const float* X = g + (size_t)e * 8 * F;
  float4 acc[8];
  #pragma unroll
  for (int bb = 0; bb < 8; bb++) acc[bb] = make_float4(0.f, 0.f, 0.f, 0.f);
  for (int ii = 0; ii < chunk; ii += 4) {
    float4 wb[4];
    #pragma unroll
    for (int u = 0; u < 4; u++) wb[u] = W[(size_t)u * (D / 4)];
    float4 xb[8];
    #pragma unroll
    for (int bb = 0; bb < 8; bb++)
      xb[bb] = *(const float4*)(X + bb * F + i0 + ii);   // wave-uniform
    #pragma unroll
    for (int u = 0; u < 4; u++) {
      #pragma unroll
      for (int bb = 0; bb < 8; bb++) {
        float xv = ((const float*)&xb[bb])[u];
        acc[bb].x += xv * wb[u].x; acc[bb].y += xv * wb[u].y;
        acc[bb].z += xv * wb[u].z; acc[bb].w += xv * wb[u].w;
      }
    }
    W += (size_t)(D / 4) * 4;
  }
  #pragma unroll
  for (int bb = 0; bb < 8; bb++)
    *(float4*)(Dp + (((size_t)blockIdx.y * 2 + e) * 8 + bb) * D + j) = acc[bb];
}

// K8: x2 = xr + top_w * sum_p Dp[p][sel]; final rmsnorm; logits. grid=B, block=256.
__global__ void k_final(const float* __restrict__ xr, const float* __restrict__ Dp,
                        const float* __restrict__ topw, const int* __restrict__ sel,
                        const float* __restrict__ flw, const float* __restrict__ sw,
                        float* __restrict__ out) {
  __shared__ float buf[4];
  int b = blockIdx.x;
  int e = sel[b];
  float tw = topw[b];
  int idx = threadIdx.x * 4;
  float4 y = make_float4(0.f, 0.f, 0.f, 0.f);
  #pragma unroll 8
  for (int p = 0; p < KSD; p++) {
    float4 v = *(const float4*)(Dp + (((size_t)p * 2 + e) * 8 + b) * D + idx);
    y.x += v.x; y.y += v.y; y.z += v.z; y.w += v.w;
  }
  float4 x = *(const float4*)(xr + b * D + idx);
  x.x += tw * y.x; x.y += tw * y.y; x.z += tw * y.z; x.w += tw * y.w;
  float ss = x.x * x.x + x.y * x.y + x.z * x.z + x.w * x.w;
  float tot = block_sum256(ss, buf);
  float sc = rsqrtf(tot * (1.f / (float)D) + 1e-6f);
  float4 wv = *(const float4*)(flw + idx);
  float xn[4];
  xn[0] = x.x * sc * wv.x; xn[1] = x.y * sc * wv.y;
  xn[2] = x.z * sc * wv.z; xn[3] = x.w * sc * wv.w;
  float l0 = 0.f, l1 = 0.f;
  #pragma unroll
  for (int r = 0; r < 4; r++) {
    l0 += xn[r] * sw[(idx + r) * 2 + 0];
    l1 += xn[r] * sw[(idx + r) * 2 + 1];
  }
  l0 = block_sum256(l0, buf);
  l1 = block_sum256(l1, buf);
  if (threadIdx.x == 0) { out[b * 2 + 0] = l0; out[b * 2 + 1] = l1; }
}

extern "C" void kernel_launch(void* const* d_in, const int* in_sizes, int n_in,
                              void* d_out, int out_size, void* d_ws, size_t ws_size,
                              hipStream_t stream) {
  const float* hs  = (const float*)d_in[0];
  const float* ln1 = (const float*)d_in[1];
  // d_in[2]=q_w, d_in[3]=k_w: dead — token-0 causal attention only needs V.
  const float* vw  = (const float*)d_in[4];
  const float* ow  = (const float*)d_in[5];
  const float* ln2 = (const float*)d_in[6];
  const float* rw  = (const float*)d_in[7];
  const float* gw  = (const float*)d_in[8];
  const float* uw  = (const float*)d_in[9];
  const float* dw  = (const float*)d_in[10];
  const float* flw = (const float*)d_in[11];
  const float* sw  = (const float*)d_in[12];

  float* ws = (float*)d_ws;
  float* h1   = ws;                 // 8192
  float* Vp   = ws + 8192;          // 32*8192   = 262144
  float* v0   = ws + 270336;        // 8192
  float* Op   = ws + 278528;        // 262144
  float* xr   = ws + 540672;        // 8192
  float* h2   = ws + 548864;        // 8192
  float* Gp   = ws + 557056;        // 16*2*8*F  = 917504
  float* Up   = ws + 1474560;       // 917504
  float* g    = ws + 2392064;       // 2*8*F     = 57344
  float* Dp   = ws + 2449408;       // 56*2*8*D  = 917504
  float* topw = ws + 3366912;       // 8
  int*   sel  = (int*)(ws + 3366920); // 8
  // no atomics anywhere -> no zero-init needed; every cell written before read.

  k_rms1<<<8, 256, 0, stream>>>(hs, ln1, h1);
  k_mvp<<<dim3(4, KSV), 64, 0, stream>>>(h1, vw, Vp);
  k_red8k<<<8, 256, 0, stream>>>(Vp, v0);
  k_mvp<<<dim3(4, KSV), 64, 0, stream>>>(v0, ow, Op);
  k_mid<<<8, 256, 0, stream>>>(hs, Op, ln2, rw, xr, h2, topw, sel);
  k_gateup<<<dim3(F / 256, KSG, 2), 64, 0, stream>>>(h2, gw, uw, Gp, Up);
  k_silu_red<<<56, 256, 0, stream>>>(Gp, Up, g);
  k_down<<<dim3(4, KSD, 2), 64, 0, stream>>>(g, dw, Dp);
  k_final<<<8, 256, 0, stream>>>(xr, Dp, topw, sel, flw, sw, (float*)d_out);
}

// Round 4
// 209.204 us; speedup vs baseline: 1.1407x; 1.1407x over previous
//
#include <hip/hip_runtime.h>
#include <math.h>

#define B 8
#define S 1024
#define D 1024
#define F 3584

#define KSV 64    // split-K for 1024x1024 matvecs: chunk 16
#define CHV 16
#define KSG 32    // split-K for gate/up: chunk 32
#define CHG 32
#define KSD 112   // split-K for down: chunk 32
#define CHD 32

#define FMA4(A, s, W) { (A).x += (s)*(W).x; (A).y += (s)*(W).y; (A).z += (s)*(W).z; (A).w += (s)*(W).w; }

// ---------------- block-wide sum for 256-thread blocks ----------------
__device__ __forceinline__ float block_sum256(float v, volatile float* buf) {
  #pragma unroll
  for (int o = 32; o; o >>= 1) v += __shfl_down(v, o);   // wave64 reduce
  __syncthreads();
  if ((threadIdx.x & 63) == 0) buf[threadIdx.x >> 6] = v;
  __syncthreads();
  return buf[0] + buf[1] + buf[2] + buf[3];
}

// K1: h1[b] = rmsnorm(hidden[b,0,:], ln1_w).  grid=B, block=256.
__global__ void k_rms1(const float* __restrict__ hs, const float* __restrict__ w,
                       float* __restrict__ h1) {
  __shared__ float buf[4];
  int b = blockIdx.x;
  int idx = threadIdx.x * 4;
  float4 x = *(const float4*)(hs + (size_t)b * S * D + idx);
  float ss = x.x * x.x + x.y * x.y + x.z * x.z + x.w * x.w;
  float tot = block_sum256(ss, buf);
  float sc = rsqrtf(tot * (1.f / (float)D) + 1e-6f);
  float4 wv = *(const float4*)(w + idx);
  float4 o;
  o.x = x.x * sc * wv.x; o.y = x.y * sc * wv.y;
  o.z = x.z * sc * wv.z; o.w = x.w * sc * wv.w;
  *(float4*)(h1 + b * D + idx) = o;
}

// Split-K matvec partials: P[p][bb][j] = sum_{i in chunk p} X[bb][i]*W[i][j].
// grid=(4, KSV), block=64. Thread: one float4 of cols, 8 batches.
__global__ __launch_bounds__(64) void k_mvp(const float* __restrict__ X,
                                            const float* __restrict__ W,
                                            float* __restrict__ P) {
  __shared__ float xs[8 * CHV];
  int i0 = blockIdx.y * CHV;
  for (int t = threadIdx.x; t < 8 * CHV; t += 64)
    xs[t] = X[(t >> 4) * D + i0 + (t & 15)];
  __syncthreads();
  int j = (blockIdx.x * 64 + threadIdx.x) * 4;
  const float4* Wp = (const float4*)(W + (size_t)i0 * D + j);
  const int st = D / 4;
  float4 acc[8];
  #pragma unroll
  for (int bb = 0; bb < 8; bb++) acc[bb] = make_float4(0.f, 0.f, 0.f, 0.f);
  #pragma unroll 1
  for (int ii = 0; ii < CHV; ii += 8) {
    float4 w0 = Wp[0 * st], w1 = Wp[1 * st], w2 = Wp[2 * st], w3 = Wp[3 * st];
    float4 w4 = Wp[4 * st], w5 = Wp[5 * st], w6 = Wp[6 * st], w7 = Wp[7 * st];
    Wp += 8 * st;
    #pragma unroll
    for (int bb = 0; bb < 8; bb++) {
      float4 xa = *(const float4*)(xs + bb * CHV + ii);
      float4 xb = *(const float4*)(xs + bb * CHV + ii + 4);
      FMA4(acc[bb], xa.x, w0); FMA4(acc[bb], xa.y, w1);
      FMA4(acc[bb], xa.z, w2); FMA4(acc[bb], xa.w, w3);
      FMA4(acc[bb], xb.x, w4); FMA4(acc[bb], xb.y, w5);
      FMA4(acc[bb], xb.z, w6); FMA4(acc[bb], xb.w, w7);
    }
  }
  #pragma unroll
  for (int bb = 0; bb < 8; bb++)
    *(float4*)(P + ((size_t)blockIdx.y * 8 + bb) * D + j) = acc[bb];
}

// Reduce KSV partials -> v0[8][1024]. grid=8, block=256.
__global__ void k_red8k(const float* __restrict__ P, float* __restrict__ v0) {
  int o = blockIdx.x * 256 + threadIdx.x;   // float4 index in [0,2048)
  const float4* P4 = (const float4*)P;
  float4 s = make_float4(0.f, 0.f, 0.f, 0.f);
  #pragma unroll 8
  for (int p = 0; p < KSV; p++) {
    float4 v = P4[(size_t)p * (8 * D / 4) + o];
    s.x += v.x; s.y += v.y; s.z += v.z; s.w += v.w;
  }
  ((float4*)v0)[o] = s;
}

// K4: xr = hidden[b,0] + sum_p Op; h2 = rmsnorm(xr, ln2); router top-1.
__global__ void k_mid(const float* __restrict__ hs, const float* __restrict__ Op,
                      const float* __restrict__ ln2, const float* __restrict__ rw,
                      float* __restrict__ xr, float* __restrict__ h2,
                      float* __restrict__ topw, int* __restrict__ sel) {
  __shared__ float buf[4];
  int b = blockIdx.x;
  int idx = threadIdx.x * 4;
  float4 x = *(const float4*)(hs + (size_t)b * S * D + idx);
  #pragma unroll 8
  for (int p = 0; p < KSV; p++) {
    float4 v = *(const float4*)(Op + ((size_t)p * 8 + b) * D + idx);
    x.x += v.x; x.y += v.y; x.z += v.z; x.w += v.w;
  }
  *(float4*)(xr + b * D + idx) = x;
  float ss = x.x * x.x + x.y * x.y + x.z * x.z + x.w * x.w;
  float tot = block_sum256(ss, buf);
  float sc = rsqrtf(tot * (1.f / (float)D) + 1e-6f);
  float4 wv = *(const float4*)(ln2 + idx);
  float4 h;
  h.x = x.x * sc * wv.x; h.y = x.y * sc * wv.y;
  h.z = x.z * sc * wv.z; h.w = x.w * sc * wv.w;
  *(float4*)(h2 + b * D + idx) = h;
  float r0 = h.x * rw[idx * 2] + h.y * rw[(idx + 1) * 2] +
             h.z * rw[(idx + 2) * 2] + h.w * rw[(idx + 3) * 2];
  float r1 = h.x * rw[idx * 2 + 1] + h.y * rw[(idx + 1) * 2 + 1] +
             h.z * rw[(idx + 2) * 2 + 1] + h.w * rw[(idx + 3) * 2 + 1];
  r0 = block_sum256(r0, buf);
  r1 = block_sum256(r1, buf);
  if (threadIdx.x == 0) {
    float m = fmaxf(r0, r1);
    float e0 = __expf(r0 - m), e1 = __expf(r1 - m);
    float inv = 1.f / (e0 + e1);
    float p0 = e0 * inv, p1 = e1 * inv;
    topw[b] = fmaxf(p0, p1);
    sel[b] = (p1 > p0) ? 1 : 0;
  }
}

// K5: split-K partials of h2 @ {gate,up}_w[e]. grid=(F/256, KSG, 4), block=64.
// z: e = z>>1, m = z&1 (0=gate,1=up). Partial layout [kc][e][8][F].
__global__ __launch_bounds__(64) void k_gateup(const float* __restrict__ h2,
                                               const float* __restrict__ gw,
                                               const float* __restrict__ uw,
                                               float* __restrict__ Gp,
                                               float* __restrict__ Up) {
  __shared__ float xs[8 * CHG];
  int e = blockIdx.z >> 1, m = blockIdx.z & 1;
  int i0 = blockIdx.y * CHG;
  for (int t = threadIdx.x; t < 8 * CHG; t += 64)
    xs[t] = h2[(t >> 5) * D + i0 + (t & 31)];
  __syncthreads();
  const float* wsrc = m ? uw : gw;
  float* out = m ? Up : Gp;
  int j = (blockIdx.x * 64 + threadIdx.x) * 4;
  const float4* Wp = (const float4*)(wsrc + (size_t)e * D * F + (size_t)i0 * F + j);
  const int st = F / 4;
  float4 acc[8];
  #pragma unroll
  for (int bb = 0; bb < 8; bb++) acc[bb] = make_float4(0.f, 0.f, 0.f, 0.f);
  #pragma unroll 1
  for (int ii = 0; ii < CHG; ii += 8) {
    float4 w0 = Wp[0 * st], w1 = Wp[1 * st], w2 = Wp[2 * st], w3 = Wp[3 * st];
    float4 w4 = Wp[4 * st], w5 = Wp[5 * st], w6 = Wp[6 * st], w7 = Wp[7 * st];
    Wp += 8 * st;
    #pragma unroll
    for (int bb = 0; bb < 8; bb++) {
      float4 xa = *(const float4*)(xs + bb * CHG + ii);
      float4 xb = *(const float4*)(xs + bb * CHG + ii + 4);
      FMA4(acc[bb], xa.x, w0); FMA4(acc[bb], xa.y, w1);
      FMA4(acc[bb], xa.z, w2); FMA4(acc[bb], xa.w, w3);
      FMA4(acc[bb], xb.x, w4); FMA4(acc[bb], xb.y, w5);
      FMA4(acc[bb], xb.z, w6); FMA4(acc[bb], xb.w, w7);
    }
  }
  #pragma unroll
  for (int bb = 0; bb < 8; bb++)
    *(float4*)(out + (((size_t)blockIdx.y * 2 + e) * 8 + bb) * F + j) = acc[bb];
}

// K6: g = silu(sum_p Gp) * (sum_p Up). grid=56, block=256.
__global__ void k_silu_red(const float* __restrict__ Gp, const float* __restrict__ Up,
                           float* __restrict__ g) {
  int o = blockIdx.x * 256 + threadIdx.x;   // float4 index in [0, 14336)
  const float4* G4 = (const float4*)Gp;
  const float4* U4 = (const float4*)Up;
  float4 ga = make_float4(0.f, 0.f, 0.f, 0.f);
  float4 ua = make_float4(0.f, 0.f, 0.f, 0.f);
  #pragma unroll 8
  for (int p = 0; p < KSG; p++) {
    float4 gv = G4[(size_t)p * (2 * 8 * F / 4) + o];
    float4 uv = U4[(size_t)p * (2 * 8 * F / 4) + o];
    ga.x += gv.x; ga.y += gv.y; ga.z += gv.z; ga.w += gv.w;
    ua.x += uv.x; ua.y += uv.y; ua.z += uv.z; ua.w += uv.w;
  }
  float4 r;
  r.x = (ga.x / (1.f + __expf(-ga.x))) * ua.x;
  r.y = (ga.y / (1.f + __expf(-ga.y))) * ua.y;
  r.z = (ga.z / (1.f + __expf(-ga.z))) * ua.z;
  r.w = (ga.w / (1.f + __expf(-ga.w))) * ua.w;
  ((float4*)g)[o] = r;
}

// K7: split-K partials of g[e][b] @ down_w[e]. grid=(4, KSD, 2), block=64.
__global__ __launch_bounds__(64) void k_down(const float* __restrict__ g,
                                             const float* __restrict__ dw,
                                             float* __restrict__ Dp) {
  __shared__ float xs[8 * CHD];
  int e = blockIdx.z;
  int i0 = blockIdx.y * CHD;
  const float* X = g + (size_t)e * 8 * F;
  for (int t = threadIdx.x; t < 8 * CHD; t += 64)
    xs[t] = X[(t >> 5) * F + i0 + (t & 31)];
  __syncthreads();
  int j = (blockIdx.x * 64 + threadIdx.x) * 4;
  const float4* Wp = (const float4*)(dw + (size_t)e * F * D + (size_t)i0 * D + j);
  const int st = D / 4;
  float4 acc[8];
  #pragma unroll
  for (int bb = 0; bb < 8; bb++) acc[bb] = make_float4(0.f, 0.f, 0.f, 0.f);
  #pragma unroll 1
  for (int ii = 0; ii < CHD; ii += 8) {
    float4 w0 = Wp[0 * st], w1 = Wp[1 * st], w2 = Wp[2 * st], w3 = Wp[3 * st];
    float4 w4 = Wp[4 * st], w5 = Wp[5 * st], w6 = Wp[6 * st], w7 = Wp[7 * st];
    Wp += 8 * st;
    #pragma unroll
    for (int bb = 0; bb < 8; bb++) {
      float4 xa = *(const float4*)(xs + bb * CHD + ii);
      float4 xb = *(const float4*)(xs + bb * CHD + ii + 4);
      FMA4(acc[bb], xa.x, w0); FMA4(acc[bb], xa.y, w1);
      FMA4(acc[bb], xa.z, w2); FMA4(acc[bb], xa.w, w3);
      FMA4(acc[bb], xb.x, w4); FMA4(acc[bb], xb.y, w5);
      FMA4(acc[bb], xb.z, w6); FMA4(acc[bb], xb.w, w7);
    }
  }
  #pragma unroll
  for (int bb = 0; bb < 8; bb++)
    *(float4*)(Dp + (((size_t)blockIdx.y * 2 + e) * 8 + bb) * D + j) = acc[bb];
}

// K8: x2 = xr + top_w * sum_p Dp[p][sel]; final rmsnorm; logits. grid=B, block=256.
__global__ void k_final(const float* __restrict__ xr, const float* __restrict__ Dp,
                        const float* __restrict__ topw, const int* __restrict__ sel,
                        const float* __restrict__ flw, const float* __restrict__ sw,
                        float* __restrict__ out) {
  __shared__ float buf[4];
  int b = blockIdx.x;
  int e = sel[b];
  float tw = topw[b];
  int idx = threadIdx.x * 4;
  float4 y = make_float4(0.f, 0.f, 0.f, 0.f);
  #pragma unroll 8
  for (int p = 0; p < KSD; p++) {
    float4 v = *(const float4*)(Dp + (((size_t)p * 2 + e) * 8 + b) * D + idx);
    y.x += v.x; y.y += v.y; y.z += v.z; y.w += v.w;
  }
  float4 x = *(const float4*)(xr + b * D + idx);
  x.x += tw * y.x; x.y += tw * y.y; x.z += tw * y.z; x.w += tw * y.w;
  float ss = x.x * x.x + x.y * x.y + x.z * x.z + x.w * x.w;
  float tot = block_sum256(ss, buf);
  float sc = rsqrtf(tot * (1.f / (float)D) + 1e-6f);
  float4 wv = *(const float4*)(flw + idx);
  float n0 = x.x * sc * wv.x, n1 = x.y * sc * wv.y;
  float n2 = x.z * sc * wv.z, n3 = x.w * sc * wv.w;
  float l0 = n0 * sw[idx * 2] + n1 * sw[(idx + 1) * 2] +
             n2 * sw[(idx + 2) * 2] + n3 * sw[(idx + 3) * 2];
  float l1 = n0 * sw[idx * 2 + 1] + n1 * sw[(idx + 1) * 2 + 1] +
             n2 * sw[(idx + 2) * 2 + 1] + n3 * sw[(idx + 3) * 2 + 1];
  l0 = block_sum256(l0, buf);
  l1 = block_sum256(l1, buf);
  if (threadIdx.x == 0) { out[b * 2 + 0] = l0; out[b * 2 + 1] = l1; }
}

extern "C" void kernel_launch(void* const* d_in, const int* in_sizes, int n_in,
                              void* d_out, int out_size, void* d_ws, size_t ws_size,
                              hipStream_t stream) {
  const float* hs  = (const float*)d_in[0];
  const float* ln1 = (const float*)d_in[1];
  // d_in[2]=q_w, d_in[3]=k_w: dead — token-0 causal attention only needs V.
  const float* vw  = (const float*)d_in[4];
  const float* ow  = (const float*)d_in[5];
  const float* ln2 = (const float*)d_in[6];
  const float* rw  = (const float*)d_in[7];
  const float* gw  = (const float*)d_in[8];
  const float* uw  = (const float*)d_in[9];
  const float* dw  = (const float*)d_in[10];
  const float* flw = (const float*)d_in[11];
  const float* sw  = (const float*)d_in[12];

  float* ws = (float*)d_ws;
  float* h1   = ws;                   // 8192
  float* Vp   = ws + 8192;            // KSV*8*D   = 524288
  float* v0   = ws + 532480;          // 8192
  float* Op   = ws + 540672;          // 524288
  float* xr   = ws + 1064960;         // 8192
  float* h2   = ws + 1073152;         // 8192
  float* Gp   = ws + 1081344;         // KSG*2*8*F = 1835008
  float* Up   = ws + 2916352;         // 1835008
  float* g    = ws + 4751360;         // 2*8*F     = 57344
  float* Dp   = ws + 4808704;         // KSD*2*8*D = 1835008
  float* topw = ws + 6643712;         // 8
  int*   sel  = (int*)(ws + 6643720); // 8
  // no atomics -> no zero-init; every partial cell is written before read.

  k_rms1<<<8, 256, 0, stream>>>(hs, ln1, h1);
  k_mvp<<<dim3(4, KSV), 64, 0, stream>>>(h1, vw, Vp);
  k_red8k<<<8, 256, 0, stream>>>(Vp, v0);
  k_mvp<<<dim3(4, KSV), 64, 0, stream>>>(v0, ow, Op);
  k_mid<<<8, 256, 0, stream>>>(hs, Op, ln2, rw, xr, h2, topw, sel);
  k_gateup<<<dim3(F / 256, KSG, 4), 64, 0, stream>>>(h2, gw, uw, Gp, Up);
  k_silu_red<<<56, 256, 0, stream>>>(Gp, Up, g);
  k_down<<<dim3(4, KSD, 2), 64, 0, stream>>>(g, dw, Dp);
  k_final<<<8, 256, 0, stream>>>(xr, Dp, topw, sel, flw, sw, (float*)d_out);
}

// Round 5
// 205.719 us; speedup vs baseline: 1.1600x; 1.0169x over previous
//
#include <hip/hip_runtime.h>
#include <math.h>

#define B 8
#define S 1024
#define D 1024
#define F 3584

#define KSV 64    // split-K for 1024x1024 matvecs: chunk 16
#define CHV 16
#define KSG 32    // split-K for gate/up: chunk 32
#define KSD 112   // split-K for down: chunk 32
#define CH32 32

#define LD4(p) (*(const float4*)(p))
#define FMA4(A, s, W) { (A).x += (s)*(W).x; (A).y += (s)*(W).y; (A).z += (s)*(W).z; (A).w += (s)*(W).w; }

// 8-row FMA step for one token-batch bb against weight batch w0..w7 (k = koff..koff+7)
#define BB8(bb, ACC, XS, CH, koff) { \
  float4 xa = LD4((XS) + (bb)*(CH) + (koff)); \
  float4 xb = LD4((XS) + (bb)*(CH) + (koff) + 4); \
  FMA4(ACC, xa.x, w0); FMA4(ACC, xa.y, w1); FMA4(ACC, xa.z, w2); FMA4(ACC, xa.w, w3); \
  FMA4(ACC, xb.x, w4); FMA4(ACC, xb.y, w5); FMA4(ACC, xb.z, w6); FMA4(ACC, xb.w, w7); }

#define ALL8(XS, CH, koff) \
  BB8(0, acc0, XS, CH, koff) BB8(1, acc1, XS, CH, koff) \
  BB8(2, acc2, XS, CH, koff) BB8(3, acc3, XS, CH, koff) \
  BB8(4, acc4, XS, CH, koff) BB8(5, acc5, XS, CH, koff) \
  BB8(6, acc6, XS, CH, koff) BB8(7, acc7, XS, CH, koff)

// ---------------- block-wide sum for 256-thread blocks ----------------
__device__ __forceinline__ float block_sum256(float v, volatile float* buf) {
  #pragma unroll
  for (int o = 32; o; o >>= 1) v += __shfl_down(v, o);   // wave64 reduce
  __syncthreads();
  if ((threadIdx.x & 63) == 0) buf[threadIdx.x >> 6] = v;
  __syncthreads();
  return buf[0] + buf[1] + buf[2] + buf[3];
}

// K1: h1[b] = rmsnorm(hidden[b,0,:], ln1_w).  grid=B, block=256.
__global__ void k_rms1(const float* __restrict__ hs, const float* __restrict__ w,
                       float* __restrict__ h1) {
  __shared__ float buf[4];
  int b = blockIdx.x;
  int idx = threadIdx.x * 4;
  float4 x = LD4(hs + (size_t)b * S * D + idx);
  float ss = x.x * x.x + x.y * x.y + x.z * x.z + x.w * x.w;
  float tot = block_sum256(ss, buf);
  float sc = rsqrtf(tot * (1.f / (float)D) + 1e-6f);
  float4 wv = LD4(w + idx);
  float4 o;
  o.x = x.x * sc * wv.x; o.y = x.y * sc * wv.y;
  o.z = x.z * sc * wv.z; o.w = x.w * sc * wv.w;
  *(float4*)(h1 + b * D + idx) = o;
}

// Split-K matvec partials: P[p][bb][j] = sum_{i in chunk p} X[bb][i]*W[i][j].
// grid=KSV, block=256. Thread: one float4 of cols (1024 cols total), 8 batches.
// 16 loads in flight per wave (all named regs).
__global__ __launch_bounds__(256, 2) void k_mvp(const float* __restrict__ X,
                                                const float* __restrict__ W,
                                                float* __restrict__ P) {
  __shared__ float xs[8 * CHV];
  int i0 = blockIdx.x * CHV;
  if (threadIdx.x < 8 * CHV)
    xs[threadIdx.x] = X[(threadIdx.x >> 4) * D + i0 + (threadIdx.x & 15)];
  __syncthreads();
  int j = threadIdx.x * 4;
  const float4* Wp = (const float4*)(W + (size_t)i0 * D + j);
  const int st = D / 4;
  float4 acc0 = {0,0,0,0}, acc1 = {0,0,0,0}, acc2 = {0,0,0,0}, acc3 = {0,0,0,0};
  float4 acc4 = {0,0,0,0}, acc5 = {0,0,0,0}, acc6 = {0,0,0,0}, acc7 = {0,0,0,0};
  {
    float4 w0 = Wp[0*st], w1 = Wp[1*st], w2 = Wp[2*st], w3 = Wp[3*st];
    float4 w4 = Wp[4*st], w5 = Wp[5*st], w6 = Wp[6*st], w7 = Wp[7*st];
    float4 v0 = Wp[8*st], v1 = Wp[9*st], v2 = Wp[10*st], v3 = Wp[11*st];
    float4 v4 = Wp[12*st], v5 = Wp[13*st], v6 = Wp[14*st], v7 = Wp[15*st];
    ALL8(xs, CHV, 0);
    w0 = v0; w1 = v1; w2 = v2; w3 = v3; w4 = v4; w5 = v5; w6 = v6; w7 = v7;
    ALL8(xs, CHV, 8);
  }
  #define MV_ST(bb, ACC) *(float4*)(P + ((size_t)blockIdx.x * 8 + (bb)) * D + j) = ACC;
  MV_ST(0, acc0) MV_ST(1, acc1) MV_ST(2, acc2) MV_ST(3, acc3)
  MV_ST(4, acc4) MV_ST(5, acc5) MV_ST(6, acc6) MV_ST(7, acc7)
  #undef MV_ST
}

// Reduce KSV partials -> v0[8][1024]. grid=8, block=256.
__global__ void k_red8k(const float* __restrict__ P, float* __restrict__ v0) {
  int o = blockIdx.x * 256 + threadIdx.x;   // float4 index in [0,2048)
  const float4* P4 = (const float4*)P;
  float4 s = {0,0,0,0};
  #pragma unroll 8
  for (int p = 0; p < KSV; p++) {
    float4 v = P4[(size_t)p * (8 * D / 4) + o];
    s.x += v.x; s.y += v.y; s.z += v.z; s.w += v.w;
  }
  ((float4*)v0)[o] = s;
}

// K4: xr = hidden[b,0] + sum_p Op; h2 = rmsnorm(xr, ln2); router top-1.
__global__ void k_mid(const float* __restrict__ hs, const float* __restrict__ Op,
                      const float* __restrict__ ln2, const float* __restrict__ rw,
                      float* __restrict__ xr, float* __restrict__ h2,
                      float* __restrict__ topw, int* __restrict__ sel) {
  __shared__ float buf[4];
  int b = blockIdx.x;
  int idx = threadIdx.x * 4;
  float4 x = LD4(hs + (size_t)b * S * D + idx);
  #pragma unroll 8
  for (int p = 0; p < KSV; p++) {
    float4 v = LD4(Op + ((size_t)p * 8 + b) * D + idx);
    x.x += v.x; x.y += v.y; x.z += v.z; x.w += v.w;
  }
  *(float4*)(xr + b * D + idx) = x;
  float ss = x.x * x.x + x.y * x.y + x.z * x.z + x.w * x.w;
  float tot = block_sum256(ss, buf);
  float sc = rsqrtf(tot * (1.f / (float)D) + 1e-6f);
  float4 wv = LD4(ln2 + idx);
  float4 h;
  h.x = x.x * sc * wv.x; h.y = x.y * sc * wv.y;
  h.z = x.z * sc * wv.z; h.w = x.w * sc * wv.w;
  *(float4*)(h2 + b * D + idx) = h;
  float r0 = h.x * rw[idx * 2] + h.y * rw[(idx + 1) * 2] +
             h.z * rw[(idx + 2) * 2] + h.w * rw[(idx + 3) * 2];
  float r1 = h.x * rw[idx * 2 + 1] + h.y * rw[(idx + 1) * 2 + 1] +
             h.z * rw[(idx + 2) * 2 + 1] + h.w * rw[(idx + 3) * 2 + 1];
  r0 = block_sum256(r0, buf);
  r1 = block_sum256(r1, buf);
  if (threadIdx.x == 0) {
    float m = fmaxf(r0, r1);
    float e0 = __expf(r0 - m), e1 = __expf(r1 - m);
    float inv = 1.f / (e0 + e1);
    float p0 = e0 * inv, p1 = e1 * inv;
    topw[b] = fmaxf(p0, p1);
    sel[b] = (p1 > p0) ? 1 : 0;
  }
}

// K5: split-K partials over flattened col space of 4 matrices
// (m=0: gate e0, m=1: gate e1, m=2: up e0, m=3: up e1; 4*F = 14336 cols).
// grid=(14, KSG), block=256. Prefetch-rotated 8-load batches.
__global__ __launch_bounds__(256, 2) void k_gateup(const float* __restrict__ h2,
                                                   const float* __restrict__ gw,
                                                   const float* __restrict__ uw,
                                                   float* __restrict__ Pgu) {
  __shared__ float xs[8 * CH32];
  int i0 = blockIdx.y * CH32;
  xs[threadIdx.x] = h2[(threadIdx.x >> 5) * D + i0 + (threadIdx.x & 31)];
  __syncthreads();
  int c = blockIdx.x * 1024 + threadIdx.x * 4;
  int m = c / F;
  int j = c - m * F;
  const float* base = (m < 2 ? gw : uw) + (size_t)(m & 1) * D * F;
  const float4* Wp = (const float4*)(base + (size_t)i0 * F + j);
  const int st = F / 4;
  float4 acc0 = {0,0,0,0}, acc1 = {0,0,0,0}, acc2 = {0,0,0,0}, acc3 = {0,0,0,0};
  float4 acc4 = {0,0,0,0}, acc5 = {0,0,0,0}, acc6 = {0,0,0,0}, acc7 = {0,0,0,0};
  float4 w0 = Wp[0*st], w1 = Wp[1*st], w2 = Wp[2*st], w3 = Wp[3*st];
  float4 w4 = Wp[4*st], w5 = Wp[5*st], w6 = Wp[6*st], w7 = Wp[7*st];
  Wp += 8 * st;
  #pragma unroll
  for (int t = 0; t < CH32 / 8 - 1; t++) {
    float4 n0 = Wp[0*st], n1 = Wp[1*st], n2 = Wp[2*st], n3 = Wp[3*st];
    float4 n4 = Wp[4*st], n5 = Wp[5*st], n6 = Wp[6*st], n7 = Wp[7*st];
    Wp += 8 * st;
    ALL8(xs, CH32, t * 8);
    w0 = n0; w1 = n1; w2 = n2; w3 = n3; w4 = n4; w5 = n5; w6 = n6; w7 = n7;
  }
  ALL8(xs, CH32, CH32 - 8);
  #define GU_ST(bb, ACC) \
    *(float4*)(Pgu + (((size_t)blockIdx.y * 4 + m) * 8 + (bb)) * F + j) = ACC;
  GU_ST(0, acc0) GU_ST(1, acc1) GU_ST(2, acc2) GU_ST(3, acc3)
  GU_ST(4, acc4) GU_ST(5, acc5) GU_ST(6, acc6) GU_ST(7, acc7)
  #undef GU_ST
}

// K6: g[e][bb][j] = silu(sum_kc gate) * (sum_kc up). grid=56, block=256.
__global__ void k_silu_red(const float* __restrict__ Pgu, float* __restrict__ g) {
  int o = blockIdx.x * 256 + threadIdx.x;     // float4 idx in [0, 14336)
  int e = o / (8 * F / 4);                     // 0..1
  int rem = o - e * (8 * F / 4);
  const float4* P4 = (const float4*)Pgu;
  float4 ga = {0,0,0,0}, ua = {0,0,0,0};
  #pragma unroll 8
  for (int kc = 0; kc < KSG; kc++) {
    float4 gv = P4[(size_t)(kc * 4 + e)     * (8 * F / 4) + rem];
    float4 uv = P4[(size_t)(kc * 4 + 2 + e) * (8 * F / 4) + rem];
    ga.x += gv.x; ga.y += gv.y; ga.z += gv.z; ga.w += gv.w;
    ua.x += uv.x; ua.y += uv.y; ua.z += uv.z; ua.w += uv.w;
  }
  float4 r;
  r.x = (ga.x / (1.f + __expf(-ga.x))) * ua.x;
  r.y = (ga.y / (1.f + __expf(-ga.y))) * ua.y;
  r.z = (ga.z / (1.f + __expf(-ga.z))) * ua.z;
  r.w = (ga.w / (1.f + __expf(-ga.w))) * ua.w;
  ((float4*)g)[o] = r;
}

// K7: split-K partials of g[e][b] @ down_w[e]. grid=(2, KSD), block=256.
__global__ __launch_bounds__(256, 2) void k_down(const float* __restrict__ g,
                                                 const float* __restrict__ dw,
                                                 float* __restrict__ Dp) {
  __shared__ float xs[8 * CH32];
  int e = blockIdx.x;
  int i0 = blockIdx.y * CH32;
  xs[threadIdx.x] = g[(size_t)e * 8 * F + (threadIdx.x >> 5) * F + i0 + (threadIdx.x & 31)];
  __syncthreads();
  int j = threadIdx.x * 4;
  const float4* Wp = (const float4*)(dw + (size_t)e * F * D + (size_t)i0 * D + j);
  const int st = D / 4;
  float4 acc0 = {0,0,0,0}, acc1 = {0,0,0,0}, acc2 = {0,0,0,0}, acc3 = {0,0,0,0};
  float4 acc4 = {0,0,0,0}, acc5 = {0,0,0,0}, acc6 = {0,0,0,0}, acc7 = {0,0,0,0};
  float4 w0 = Wp[0*st], w1 = Wp[1*st], w2 = Wp[2*st], w3 = Wp[3*st];
  float4 w4 = Wp[4*st], w5 = Wp[5*st], w6 = Wp[6*st], w7 = Wp[7*st];
  Wp += 8 * st;
  #pragma unroll
  for (int t = 0; t < CH32 / 8 - 1; t++) {
    float4 n0 = Wp[0*st], n1 = Wp[1*st], n2 = Wp[2*st], n3 = Wp[3*st];
    float4 n4 = Wp[4*st], n5 = Wp[5*st], n6 = Wp[6*st], n7 = Wp[7*st];
    Wp += 8 * st;
    ALL8(xs, CH32, t * 8);
    w0 = n0; w1 = n1; w2 = n2; w3 = n3; w4 = n4; w5 = n5; w6 = n6; w7 = n7;
  }
  ALL8(xs, CH32, CH32 - 8);
  #define DN_ST(bb, ACC) \
    *(float4*)(Dp + (((size_t)blockIdx.y * 2 + e) * 8 + (bb)) * D + j) = ACC;
  DN_ST(0, acc0) DN_ST(1, acc1) DN_ST(2, acc2) DN_ST(3, acc3)
  DN_ST(4, acc4) DN_ST(5, acc5) DN_ST(6, acc6) DN_ST(7, acc7)
  #undef DN_ST
}

// K8: x2 = xr + top_w * sum_p Dp[p][sel]; final rmsnorm; logits. grid=B, block=256.
__global__ void k_final(const float* __restrict__ xr, const float* __restrict__ Dp,
                        const float* __restrict__ topw, const int* __restrict__ sel,
                        const float* __restrict__ flw, const float* __restrict__ sw,
                        float* __restrict__ out) {
  __shared__ float buf[4];
  int b = blockIdx.x;
  int e = sel[b];
  float tw = topw[b];
  int idx = threadIdx.x * 4;
  float4 y = {0,0,0,0};
  #pragma unroll 8
  for (int p = 0; p < KSD; p++) {
    float4 v = LD4(Dp + (((size_t)p * 2 + e) * 8 + b) * D + idx);
    y.x += v.x; y.y += v.y; y.z += v.z; y.w += v.w;
  }
  float4 x = LD4(xr + b * D + idx);
  x.x += tw * y.x; x.y += tw * y.y; x.z += tw * y.z; x.w += tw * y.w;
  float ss = x.x * x.x + x.y * x.y + x.z * x.z + x.w * x.w;
  float tot = block_sum256(ss, buf);
  float sc = rsqrtf(tot * (1.f / (float)D) + 1e-6f);
  float4 wv = LD4(flw + idx);
  float n0 = x.x * sc * wv.x, n1 = x.y * sc * wv.y;
  float n2 = x.z * sc * wv.z, n3 = x.w * sc * wv.w;
  float l0 = n0 * sw[idx * 2] + n1 * sw[(idx + 1) * 2] +
             n2 * sw[(idx + 2) * 2] + n3 * sw[(idx + 3) * 2];
  float l1 = n0 * sw[idx * 2 + 1] + n1 * sw[(idx + 1) * 2 + 1] +
             n2 * sw[(idx + 2) * 2 + 1] + n3 * sw[(idx + 3) * 2 + 1];
  l0 = block_sum256(l0, buf);
  l1 = block_sum256(l1, buf);
  if (threadIdx.x == 0) { out[b * 2 + 0] = l0; out[b * 2 + 1] = l1; }
}

extern "C" void kernel_launch(void* const* d_in, const int* in_sizes, int n_in,
                              void* d_out, int out_size, void* d_ws, size_t ws_size,
                              hipStream_t stream) {
  const float* hs  = (const float*)d_in[0];
  const float* ln1 = (const float*)d_in[1];
  // d_in[2]=q_w, d_in[3]=k_w: dead — token-0 causal attention only needs V.
  const float* vw  = (const float*)d_in[4];
  const float* ow  = (const float*)d_in[5];
  const float* ln2 = (const float*)d_in[6];
  const float* rw  = (const float*)d_in[7];
  const float* gw  = (const float*)d_in[8];
  const float* uw  = (const float*)d_in[9];
  const float* dw  = (const float*)d_in[10];
  const float* flw = (const float*)d_in[11];
  const float* sw  = (const float*)d_in[12];

  float* ws = (float*)d_ws;
  float* h1   = ws;                   // 8192
  float* Vp   = ws + 8192;            // KSV*8*D    = 524288
  float* v0   = ws + 532480;          // 8192
  float* Op   = ws + 540672;          // 524288
  float* xr   = ws + 1064960;         // 8192
  float* h2   = ws + 1073152;         // 8192
  float* Pgu  = ws + 1081344;         // KSG*4*8*F  = 3670016
  float* g    = ws + 4751360;         // 2*8*F      = 57344
  float* Dp   = ws + 4808704;         // KSD*2*8*D  = 1835008
  float* topw = ws + 6643712;         // 8
  int*   sel  = (int*)(ws + 6643720); // 8
  // no atomics -> no zero-init; every partial cell is written before read.

  k_rms1<<<8, 256, 0, stream>>>(hs, ln1, h1);
  k_mvp<<<KSV, 256, 0, stream>>>(h1, vw, Vp);
  k_red8k<<<8, 256, 0, stream>>>(Vp, v0);
  k_mvp<<<KSV, 256, 0, stream>>>(v0, ow, Op);
  k_mid<<<8, 256, 0, stream>>>(hs, Op, ln2, rw, xr, h2, topw, sel);
  k_gateup<<<dim3(14, KSG), 256, 0, stream>>>(h2, gw, uw, Pgu);
  k_silu_red<<<56, 256, 0, stream>>>(Pgu, g);
  k_down<<<dim3(2, KSD), 256, 0, stream>>>(g, dw, Dp);
  k_final<<<8, 256, 0, stream>>>(xr, Dp, topw, sel, flw, sw, (float*)d_out);
}